// Round 6
// baseline (2599.054 us; speedup 1.0000x reference)
//
#include <hip/hip_runtime.h>

typedef _Float16 half8 __attribute__((ext_vector_type(8)));
typedef _Float16 f16x2 __attribute__((ext_vector_type(2)));
typedef float floatx4 __attribute__((ext_vector_type(4)));

#define NB 256    // batch
#define NT 512    // time
#define NI 64     // input
#define NH 256    // hidden
#define NSEQ 16   // sequences per block
#define NBLK (NB / NSEQ)   // 16 blocks
#define THR 512            // 8 waves, 2 waves/SIMD
#define HS 344             // H row stride in f16

// B-fragment pack (VALIDATED R9/R10): 480 frags x 64 lanes x 8 f16.
// Cols: [0,256)=r, [256,512)=z, [512,768)=h_n, [768,1024)=i_n. K: [0,256)=h, [256,320)=x.
// frag f: r: tt*10+kb; z: 160+tt*10+kb; h_n: 320+tt*8+kb (kb<8); i_n: 448+tt*2+(kb-8).
// wb[f*512 + lane*8 + i] = W[k = kb*32 + (lane>>4)*8 + i][n = tt*16 + (lane&15)]
#define WB_N (480 * 512)

__global__ __launch_bounds__(256) void gru_prep_kernel(
    const float* __restrict__ w_ih, const float* __restrict__ w_hh,
    _Float16* __restrict__ wb)
{
  int n = blockIdx.x * 256 + threadIdx.x;
  if (n >= WB_N) return;
  int i = n & 7, l = (n >> 3) & 63, f = n >> 9;
  int q = l >> 4, col = l & 15;
  int tt, kb, gate;
  if (f < 160)      { tt = f / 10;               kb = f % 10;        gate = 0; }
  else if (f < 320) { int f2 = f - 160; tt = f2 / 10; kb = f2 % 10;  gate = 1; }
  else if (f < 448) { int f3 = f - 320; tt = f3 / 8;  kb = f3 % 8;   gate = 2; }
  else              { int f4 = f - 448; tt = f4 / 2;  kb = 8 + (f4 & 1); gate = 3; }
  int j = (tt & 15) * 16 + col;
  int k = kb * 32 + q * 8 + i;
  float v;
  if (gate == 0)      v = (k < 256) ? w_hh[(0   + j) * 256 + k] : w_ih[(0   + j) * 64 + (k - 256)];
  else if (gate == 1) v = (k < 256) ? w_hh[(256 + j) * 256 + k] : w_ih[(256 + j) * 64 + (k - 256)];
  else if (gate == 2) v = w_hh[(512 + j) * 256 + k];
  else                v = w_ih[(512 + j) * 64 + (k - 256)];
  wb[n] = (_Float16)v;
}

__device__ __forceinline__ float sigm(float v) {
  return __builtin_amdgcn_rcpf(1.0f + __expf(-v));
}
__device__ __forceinline__ float tanh_f(float v) {
  return 1.0f - 2.0f * __builtin_amdgcn_rcpf(1.0f + __expf(2.0f * v));
}

#define MFMA16(a, b, c) __builtin_amdgcn_mfma_f32_16x16x32_f16(a, b, c, 0, 0, 0)
#define FDOT(W, X, A) __builtin_amdgcn_fdot2(__builtin_bit_cast(f16x2, W), \
                                             __builtin_bit_cast(f16x2, X), A, false)

// ---------------- batched MFMA recurrence: 1 block = 16 sequences ----------------
// R16: the whole B-operand moves to AGPRs. R10-R15 post-mortems: the allocator
// NEVER keeps >~100 regs of long-lived "v"-class values live (it spills, and each
// spilled frag is reloaded from L2-backed scratch every step; dur always fit
// (B-bytes restreamed)/64 B/cyc). gfx950 MFMA reads A/B operands DIRECTLY from
// AGPRs (cdna4_isa §10) — a second 256-reg/wave file the VALU/epilogue never
// competes for. Pin all 60 B-frags/wave (r,z: 10 kb x 2 tiles x 2; n_h: 8 x 2;
// i_n: 2 x 2) = 240 AGPRs via asm "+a". 8 waves x 30 KB = the block's whole
// B-slice resident. No WN staging, no L2 streams, no scratch.
// Per-step/CU: LDS ~1500 cyc (80 A-frag b128 reads + gate/xv writes + HD read) =
// binding; MFMA 580/SIMD; epilogue VALU ~800/SIMD; VMEM trivial. ~0.8 us/step.
__global__ __launch_bounds__(THR, 2) void gru_kernel(
    const float* __restrict__ x,      // [B, T, I]
    const float* __restrict__ b_ih,   // [768]
    const float* __restrict__ b_hh,   // [768]
    const _Float16* __restrict__ wb,  // packed B fragments
    _Float16* __restrict__ HD,        // [NT][NB][NH] f16 hidden-state dump
    float* __restrict__ out)          // unused here (kept for symmetry)
{
  __shared__ __align__(16) _Float16 H[2][NSEQ][HS];   // 22016 B, double-buffered

  const int tid  = threadIdx.x;
  const int lane = tid & 63;
  const int w    = tid >> 6;        // wave 0..7
  const int q    = lane >> 4;       // quad 0..3
  const int col  = lane & 15;
  const int b0   = blockIdx.x * NSEQ;
  const int j0   = (2 * w) * 16 + col;      // tile t0 = 2w
  const int j1   = j0 + 16;                 // tile t1 = 2w+1

  const _Float16* wbL = wb + (size_t)lane * 8;

  // ---- ALL B fragments pinned in AGPRs: 60 x half8 = 240 a-regs ----
#define LR(T, k) half8 R##T##_##k = *(const half8*)(wbL + (size_t)((2 * w + T) * 10 + (k)) * 512);
  LR(0,0) LR(0,1) LR(0,2) LR(0,3) LR(0,4) LR(0,5) LR(0,6) LR(0,7) LR(0,8) LR(0,9)
  LR(1,0) LR(1,1) LR(1,2) LR(1,3) LR(1,4) LR(1,5) LR(1,6) LR(1,7) LR(1,8) LR(1,9)
#undef LR
#define LZ(T, k) half8 Z##T##_##k = *(const half8*)(wbL + (size_t)(160 + (2 * w + T) * 10 + (k)) * 512);
  LZ(0,0) LZ(0,1) LZ(0,2) LZ(0,3) LZ(0,4) LZ(0,5) LZ(0,6) LZ(0,7) LZ(0,8) LZ(0,9)
  LZ(1,0) LZ(1,1) LZ(1,2) LZ(1,3) LZ(1,4) LZ(1,5) LZ(1,6) LZ(1,7) LZ(1,8) LZ(1,9)
#undef LZ
#define LN(T, k) half8 N##T##_##k = *(const half8*)(wbL + (size_t)(320 + (2 * w + T) * 8 + (k)) * 512);
  LN(0,0) LN(0,1) LN(0,2) LN(0,3) LN(0,4) LN(0,5) LN(0,6) LN(0,7)
  LN(1,0) LN(1,1) LN(1,2) LN(1,3) LN(1,4) LN(1,5) LN(1,6) LN(1,7)
#undef LN
  half8 I0_0 = *(const half8*)(wbL + (size_t)(448 + (2 * w) * 2 + 0) * 512);
  half8 I0_1 = *(const half8*)(wbL + (size_t)(448 + (2 * w) * 2 + 1) * 512);
  half8 I1_0 = *(const half8*)(wbL + (size_t)(448 + (2 * w + 1) * 2 + 0) * 512);
  half8 I1_1 = *(const half8*)(wbL + (size_t)(448 + (2 * w + 1) * 2 + 1) * 512);
  // Pin to AGPR class: opaque (non-remat) AND outside the contested v-file.
  asm("" : "+a"(R0_0), "+a"(R0_1), "+a"(R0_2), "+a"(R0_3), "+a"(R0_4),
           "+a"(R0_5), "+a"(R0_6), "+a"(R0_7), "+a"(R0_8), "+a"(R0_9));
  asm("" : "+a"(R1_0), "+a"(R1_1), "+a"(R1_2), "+a"(R1_3), "+a"(R1_4),
           "+a"(R1_5), "+a"(R1_6), "+a"(R1_7), "+a"(R1_8), "+a"(R1_9));
  asm("" : "+a"(Z0_0), "+a"(Z0_1), "+a"(Z0_2), "+a"(Z0_3), "+a"(Z0_4),
           "+a"(Z0_5), "+a"(Z0_6), "+a"(Z0_7), "+a"(Z0_8), "+a"(Z0_9));
  asm("" : "+a"(Z1_0), "+a"(Z1_1), "+a"(Z1_2), "+a"(Z1_3), "+a"(Z1_4),
           "+a"(Z1_5), "+a"(Z1_6), "+a"(Z1_7), "+a"(Z1_8), "+a"(Z1_9));
  asm("" : "+a"(N0_0), "+a"(N0_1), "+a"(N0_2), "+a"(N0_3),
           "+a"(N0_4), "+a"(N0_5), "+a"(N0_6), "+a"(N0_7));
  asm("" : "+a"(N1_0), "+a"(N1_1), "+a"(N1_2), "+a"(N1_3),
           "+a"(N1_4), "+a"(N1_5), "+a"(N1_6), "+a"(N1_7));
  asm("" : "+a"(I0_0), "+a"(I0_1), "+a"(I1_0), "+a"(I1_1));

  const float br0  = b_ih[j0] + b_hh[j0];
  const float bz0  = b_ih[256 + j0] + b_hh[256 + j0];
  const float bin0 = b_ih[512 + j0];
  const float bhn0 = b_hh[512 + j0];
  const float br1  = b_ih[j1] + b_hh[j1];
  const float bz1  = b_ih[256 + j1] + b_hh[256 + j1];
  const float bin1 = b_ih[512 + j1];
  const float bhn1 = b_hh[512 + j1];

  // ---- init: zero H (both buffers), then x(t=0) into H[0] ----
  {
    float4* hz = (float4*)H;
    #pragma unroll
    for (int it = 0; it < 3; ++it) {
      int idx = tid + it * THR;
      if (idx < (int)(sizeof(H) / 16)) hz[idx] = float4{0, 0, 0, 0};
    }
  }
  __syncthreads();
  H[0][w][256 + lane]     = (_Float16)x[(size_t)(b0 + w)     * (NT * NI) + lane];
  H[0][w + 8][256 + lane] = (_Float16)x[(size_t)(b0 + w + 8) * (NT * NI) + lane];
  float h00 = 0.0f, h01 = 0.0f, h02 = 0.0f, h03 = 0.0f;
  float h10 = 0.0f, h11 = 0.0f, h12 = 0.0f, h13 = 0.0f;
  const float* xp0 = x + (size_t)(b0 + w)     * (NT * NI) + 64 + lane;
  const float* xp1 = x + (size_t)(b0 + w + 8) * (NT * NI) + 64 + lane;
  __syncthreads();

  for (int t = 0; t < NT; ++t) {
    const int cur = t & 1, nxt = cur ^ 1;

    float xv0 = 0.0f, xv1 = 0.0f;
    if (t + 1 < NT) { xv0 = xp0[(size_t)t * 64]; xv1 = xp1[(size_t)t * 64]; }

    // ---- dump h_{t-1} (h-part of H[cur]) to HD[t-1]: all 512 threads ----
    if (t > 0) {
      int row = tid >> 5, ch = tid & 31;
      float4 hv = *(const float4*)&H[cur][row][ch * 8];
      *(float4*)(HD + ((size_t)(t - 1) * NB + b0 + row) * NH + ch * 8) = hv;
    }

    // ---- GEMM: A row = seq = col (validated), 60 MFMAs/wave, B all-AGPR ----
    const _Float16* hrow = &H[cur][col][q * 8];
    floatx4 cR0 = {0,0,0,0}, cZ0 = {0,0,0,0}, cN0 = {0,0,0,0}, cI0 = {0,0,0,0};
    floatx4 cR1 = {0,0,0,0}, cZ1 = {0,0,0,0}, cN1 = {0,0,0,0}, cI1 = {0,0,0,0};
#define KGRP(k) { \
    half8 a = *(const half8*)(hrow + (k) * 32); \
    cR0 = MFMA16(a, R0_##k, cR0); cR1 = MFMA16(a, R1_##k, cR1); \
    cZ0 = MFMA16(a, Z0_##k, cZ0); cZ1 = MFMA16(a, Z1_##k, cZ1); \
    cN0 = MFMA16(a, N0_##k, cN0); cN1 = MFMA16(a, N1_##k, cN1); }
    KGRP(0) KGRP(1) KGRP(2) KGRP(3) KGRP(4) KGRP(5) KGRP(6) KGRP(7)
#undef KGRP
    // k=8,9: x-columns — r_x/z_x/i_n all AGPR-resident
    { half8 a = *(const half8*)(hrow + 8 * 32);
      cR0 = MFMA16(a, R0_8, cR0); cR1 = MFMA16(a, R1_8, cR1);
      cZ0 = MFMA16(a, Z0_8, cZ0); cZ1 = MFMA16(a, Z1_8, cZ1);
      cI0 = MFMA16(a, I0_0, cI0); cI1 = MFMA16(a, I1_0, cI1); }
    { half8 a = *(const half8*)(hrow + 9 * 32);
      cR0 = MFMA16(a, R0_9, cR0); cR1 = MFMA16(a, R1_9, cR1);
      cZ0 = MFMA16(a, Z0_9, cZ0); cZ1 = MFMA16(a, Z1_9, cZ1);
      cI0 = MFMA16(a, I0_1, cI0); cI1 = MFMA16(a, I1_1, cI1); }

    // ---- in-register epilogue: lane owns (j0,j1) x (seqs q*4..q*4+3) ----
#define GATE(m, hvar, CR, CZ, CN, CI, BR_, BZ_, BI_, BH_, J) { \
    float rr = sigm(CR[m] + BR_); \
    float zz = sigm(CZ[m] + BZ_); \
    float nn = tanh_f(CI[m] + BI_ + rr * (CN[m] + BH_)); \
    hvar = (1.0f - zz) * nn + zz * hvar; \
    H[nxt][q * 4 + (m)][J] = (_Float16)hvar; }
    GATE(0, h00, cR0, cZ0, cN0, cI0, br0, bz0, bin0, bhn0, j0)
    GATE(1, h01, cR0, cZ0, cN0, cI0, br0, bz0, bin0, bhn0, j0)
    GATE(2, h02, cR0, cZ0, cN0, cI0, br0, bz0, bin0, bhn0, j0)
    GATE(3, h03, cR0, cZ0, cN0, cI0, br0, bz0, bin0, bhn0, j0)
    GATE(0, h10, cR1, cZ1, cN1, cI1, br1, bz1, bin1, bhn1, j1)
    GATE(1, h11, cR1, cZ1, cN1, cI1, br1, bz1, bin1, bhn1, j1)
    GATE(2, h12, cR1, cZ1, cN1, cI1, br1, bz1, bin1, bhn1, j1)
    GATE(3, h13, cR1, cZ1, cN1, cI1, br1, bz1, bin1, bhn1, j1)
#undef GATE
    if (t + 1 < NT) {
      H[nxt][w][256 + lane]     = (_Float16)xv0;
      H[nxt][w + 8][256 + lane] = (_Float16)xv1;
    }

    __syncthreads();   // the single per-step barrier
  }

  // ---- final dump: h_{NT-1} lives in H[0] (NT even) ----
  {
    int row = tid >> 5, ch = tid & 31;
    float4 hv = *(const float4*)&H[0][row][ch * 8];
    *(float4*)(HD + ((size_t)(NT - 1) * NB + b0 + row) * NH + ch * 8) = hv;
  }
}

// ---------------- epilogue: out[t][b] = HD[t][b][:] . w_out + b_out ----------------
__global__ __launch_bounds__(256) void gru_out_kernel(
    const _Float16* __restrict__ HD, const float* __restrict__ w_out,
    const float* __restrict__ b_out, float* __restrict__ out)
{
  __shared__ __align__(16) _Float16 WL[NH];
  int tid = threadIdx.x;
  WL[tid] = (_Float16)w_out[tid];
  __syncthreads();
  int gid = blockIdx.x * 256 + tid;          // gid = t*NB + b
  const float4* hp = (const float4*)(HD + (size_t)gid * NH);
  const float4* wp = (const float4*)WL;
  float acc = 0.0f;
  #pragma unroll
  for (int i = 0; i < NH / 8; ++i) {
    float4 hv = hp[i];
    float4 wv = wp[i];
    acc = FDOT(hv.x, wv.x, acc);
    acc = FDOT(hv.y, wv.y, acc);
    acc = FDOT(hv.z, wv.z, acc);
    acc = FDOT(hv.w, wv.w, acc);
  }
  out[gid] = acc + b_out[0];
}

extern "C" void kernel_launch(void* const* d_in, const int* in_sizes, int n_in,
                              void* d_out, int out_size, void* d_ws, size_t ws_size,
                              hipStream_t stream) {
  const float* x     = (const float*)d_in[0];
  const float* w_ih  = (const float*)d_in[1];
  const float* w_hh  = (const float*)d_in[2];
  const float* b_ih  = (const float*)d_in[3];
  const float* b_hh  = (const float*)d_in[4];
  const float* w_out = (const float*)d_in[5];
  const float* b_out = (const float*)d_in[6];
  float* out = (float*)d_out;

  _Float16* wb = (_Float16*)d_ws;            // 480 KB packed B fragments
  _Float16* HD = wb + WB_N;                  // 64 MB hidden-state dump (16B-aligned)

  gru_prep_kernel<<<(WB_N + 255) / 256, 256, 0, stream>>>(w_ih, w_hh, wb);
  gru_kernel<<<NBLK, THR, 0, stream>>>(x, b_ih, b_hh, wb, HD, out);
  gru_out_kernel<<<(NT * NB) / 256, 256, 0, stream>>>(HD, w_out, b_out, out);
}

// Round 7
// 1286.333 us; speedup vs baseline: 2.0205x; 2.0205x over previous
//
#include <hip/hip_runtime.h>

typedef _Float16 half8 __attribute__((ext_vector_type(8)));
typedef _Float16 f16x2 __attribute__((ext_vector_type(2)));
typedef float floatx4 __attribute__((ext_vector_type(4)));

#define NB 256    // batch
#define NT 512    // time
#define NI 64     // input
#define NH 256    // hidden
#define NSEQ 16   // sequences per block
#define NBLK (NB / NSEQ)   // 16 blocks
#define THR 512            // 8 waves, 2 waves/SIMD
#define HS 344             // H row stride in f16

// B-fragment pack (VALIDATED R9/R10): 480 frags x 64 lanes x 8 f16.
// Cols: [0,256)=r, [256,512)=z, [512,768)=h_n, [768,1024)=i_n. K: [0,256)=h, [256,320)=x.
// frag f: r: tt*10+kb; z: 160+tt*10+kb; h_n: 320+tt*8+kb (kb<8); i_n: 448+tt*2+(kb-8).
// wb[f*512 + lane*8 + i] = W[k = kb*32 + (lane>>4)*8 + i][n = tt*16 + (lane&15)]
#define WB_N (480 * 512)

__global__ __launch_bounds__(256) void gru_prep_kernel(
    const float* __restrict__ w_ih, const float* __restrict__ w_hh,
    _Float16* __restrict__ wb)
{
  int n = blockIdx.x * 256 + threadIdx.x;
  if (n >= WB_N) return;
  int i = n & 7, l = (n >> 3) & 63, f = n >> 9;
  int q = l >> 4, col = l & 15;
  int tt, kb, gate;
  if (f < 160)      { tt = f / 10;               kb = f % 10;        gate = 0; }
  else if (f < 320) { int f2 = f - 160; tt = f2 / 10; kb = f2 % 10;  gate = 1; }
  else if (f < 448) { int f3 = f - 320; tt = f3 / 8;  kb = f3 % 8;   gate = 2; }
  else              { int f4 = f - 448; tt = f4 / 2;  kb = 8 + (f4 & 1); gate = 3; }
  int j = (tt & 15) * 16 + col;
  int k = kb * 32 + q * 8 + i;
  float v;
  if (gate == 0)      v = (k < 256) ? w_hh[(0   + j) * 256 + k] : w_ih[(0   + j) * 64 + (k - 256)];
  else if (gate == 1) v = (k < 256) ? w_hh[(256 + j) * 256 + k] : w_ih[(256 + j) * 64 + (k - 256)];
  else if (gate == 2) v = w_hh[(512 + j) * 256 + k];
  else                v = w_ih[(512 + j) * 64 + (k - 256)];
  wb[n] = (_Float16)v;
}

__device__ __forceinline__ float sigm(float v) {
  return __builtin_amdgcn_rcpf(1.0f + __expf(-v));
}
__device__ __forceinline__ float tanh_f(float v) {
  return 1.0f - 2.0f * __builtin_amdgcn_rcpf(1.0f + __expf(2.0f * v));
}

#define MFMA16(a, b, c) __builtin_amdgcn_mfma_f32_16x16x32_f16(a, b, c, 0, 0, 0)
#define FDOT(W, X, A) __builtin_amdgcn_fdot2(__builtin_bit_cast(f16x2, W), \
                                             __builtin_bit_cast(f16x2, X), A, false)

// ---------------- batched MFMA recurrence: 1 block = 16 sequences ----------------
// R17 = R12 structure with the two fixes the 6-round post-mortem isolated:
//  1. amdgpu_waves_per_eu(2,2): __launch_bounds__(512,2) only sets a MINIMUM
//     waves/EU; the backend's occupancy heuristic still targeted 4 waves/SIMD and
//     clamped the allocator to 128 regs (every min=2 build reported exactly 128;
//     the min=1 build reported 244). Pinning min=max=2 sets the budget to 256.
//  2. r/z pins in "+a" (AGPR class): gfx950 has a UNIFIED 256-reg budget (R16's
//     240a+128v=368 proved it the hard way), but WITHIN that budget the a-class
//     has no other users (accumulators stay v-side), so the 128 pinned regs stop
//     competing with VALU temps in the v-class where the allocator has refused
//     residency 6 rounds running. MFMA reads B directly from AGPRs (isa §10).
// Demand: 128a + ~110v = 238 <= 256. n-gate frags in LDS (128 KB), i_n streamed
// from L2 (32 KB/step, VMEM pipe, also the allocator's relief valve).
// Per-step/CU at residency: LDS ~3000 cyc (A 80 + WN 128 reads + writes + HD) =
// binding; MFMA 580/SIMD; VMEM ~550; epilogue VALU — all overlapped. ~650 us.
__global__ __attribute__((amdgpu_waves_per_eu(2, 2))) __launch_bounds__(THR)
void gru_kernel(
    const float* __restrict__ x,      // [B, T, I]
    const float* __restrict__ b_ih,   // [768]
    const float* __restrict__ b_hh,   // [768]
    const _Float16* __restrict__ wb,  // packed B fragments
    _Float16* __restrict__ HD,        // [NT][NB][NH] f16 hidden-state dump
    float* __restrict__ out)          // unused here (kept for symmetry)
{
  __shared__ __align__(16) _Float16 H[2][NSEQ][HS];   // 22016 B, double-buffered
  __shared__ __align__(16) _Float16 WN[128 * 512];    // 131072 B: n-gate frags (16 tiles)

  const int tid  = threadIdx.x;
  const int lane = tid & 63;
  const int w    = tid >> 6;        // wave 0..7
  const int q    = lane >> 4;       // quad 0..3
  const int col  = lane & 15;
  const int b0   = blockIdx.x * NSEQ;
  const int j0   = (2 * w) * 16 + col;      // tile t0 = 2w
  const int j1   = j0 + 16;                 // tile t1 = 2w+1

  const _Float16* wbL = wb + (size_t)lane * 8;

  // ---- stage n-gate frags (wb frags [320,448)) to LDS: 128 KB coalesced ----
  {
    const float4* src = (const float4*)(wb + (size_t)320 * 512);
    float4* dst = (float4*)WN;
    #pragma unroll
    for (int it = 0; it < 16; ++it) dst[tid + it * THR] = src[tid + it * THR];
  }
  // wave's n frags: tile t0 -> frag 16w + k, tile t1 -> frag 16w+8+k
  const _Float16* wnW = WN + (size_t)(16 * w) * 512 + (size_t)lane * 8;

  // ---- persistent B fragments: r + z both tiles (32 x half8 = 128 AGPRs) ----
#define LR(T, k) half8 R##T##_##k = *(const half8*)(wbL + (size_t)((2 * w + T) * 10 + (k)) * 512);
  LR(0,0) LR(0,1) LR(0,2) LR(0,3) LR(0,4) LR(0,5) LR(0,6) LR(0,7) LR(0,8) LR(0,9)
  LR(1,0) LR(1,1) LR(1,2) LR(1,3) LR(1,4) LR(1,5) LR(1,6) LR(1,7) LR(1,8) LR(1,9)
#undef LR
#define LZ(T, k) half8 Z##T##_##k = *(const half8*)(wbL + (size_t)(160 + (2 * w + T) * 10 + (k)) * 512);
  LZ(0,0) LZ(0,1) LZ(0,2) LZ(0,3) LZ(0,4) LZ(0,5) LZ(0,6) LZ(0,7) LZ(0,8) LZ(0,9)
  LZ(1,0) LZ(1,1) LZ(1,2) LZ(1,3) LZ(1,4) LZ(1,5) LZ(1,6) LZ(1,7) LZ(1,8) LZ(1,9)
#undef LZ
  // Pin to the (otherwise unused) a-class: opaque -> non-remat -> resident.
  asm("" : "+a"(R0_0), "+a"(R0_1), "+a"(R0_2), "+a"(R0_3), "+a"(R0_4),
           "+a"(R0_5), "+a"(R0_6), "+a"(R0_7), "+a"(R0_8), "+a"(R0_9));
  asm("" : "+a"(R1_0), "+a"(R1_1), "+a"(R1_2), "+a"(R1_3), "+a"(R1_4),
           "+a"(R1_5), "+a"(R1_6), "+a"(R1_7), "+a"(R1_8), "+a"(R1_9));
  asm("" : "+a"(Z0_0), "+a"(Z0_1), "+a"(Z0_2), "+a"(Z0_3), "+a"(Z0_4),
           "+a"(Z0_5), "+a"(Z0_6), "+a"(Z0_7), "+a"(Z0_8), "+a"(Z0_9));
  asm("" : "+a"(Z1_0), "+a"(Z1_1), "+a"(Z1_2), "+a"(Z1_3), "+a"(Z1_4),
           "+a"(Z1_5), "+a"(Z1_6), "+a"(Z1_7), "+a"(Z1_8), "+a"(Z1_9));

  // ---- i_n stream pointers (2 frags/tile, L2 re-read each step; loop-variant) ----
  uintptr_t pI0 = (uintptr_t)(wbL + (size_t)(448 + (2 * w) * 2) * 512);
  uintptr_t pI1 = (uintptr_t)(wbL + (size_t)(448 + (2 * w + 1) * 2) * 512);

  const float br0  = b_ih[j0] + b_hh[j0];
  const float bz0  = b_ih[256 + j0] + b_hh[256 + j0];
  const float bin0 = b_ih[512 + j0];
  const float bhn0 = b_hh[512 + j0];
  const float br1  = b_ih[j1] + b_hh[j1];
  const float bz1  = b_ih[256 + j1] + b_hh[256 + j1];
  const float bin1 = b_ih[512 + j1];
  const float bhn1 = b_hh[512 + j1];

  // ---- init: zero H (both buffers), then x(t=0) into H[0] ----
  {
    float4* hz = (float4*)H;
    #pragma unroll
    for (int it = 0; it < 3; ++it) {
      int idx = tid + it * THR;
      if (idx < (int)(sizeof(H) / 16)) hz[idx] = float4{0, 0, 0, 0};
    }
  }
  __syncthreads();
  H[0][w][256 + lane]     = (_Float16)x[(size_t)(b0 + w)     * (NT * NI) + lane];
  H[0][w + 8][256 + lane] = (_Float16)x[(size_t)(b0 + w + 8) * (NT * NI) + lane];
  float h00 = 0.0f, h01 = 0.0f, h02 = 0.0f, h03 = 0.0f;
  float h10 = 0.0f, h11 = 0.0f, h12 = 0.0f, h13 = 0.0f;
  const float* xp0 = x + (size_t)(b0 + w)     * (NT * NI) + 64 + lane;
  const float* xp1 = x + (size_t)(b0 + w + 8) * (NT * NI) + 64 + lane;
  __syncthreads();

  for (int t = 0; t < NT; ++t) {
    const int cur = t & 1, nxt = cur ^ 1;
    // keep i-stream loads loop-variant (no LICM hoist -> no extra v-pressure)
    asm("" : "+v"(pI0), "+v"(pI1));
    const half8* sI0 = (const half8*)pI0;
    const half8* sI1 = (const half8*)pI1;

    float xv0 = 0.0f, xv1 = 0.0f;
    if (t + 1 < NT) { xv0 = xp0[(size_t)t * 64]; xv1 = xp1[(size_t)t * 64]; }

    // ---- dump h_{t-1} (h-part of H[cur]) to HD[t-1]: all 512 threads ----
    if (t > 0) {
      int row = tid >> 5, ch = tid & 31;
      float4 hv = *(const float4*)&H[cur][row][ch * 8];
      *(float4*)(HD + ((size_t)(t - 1) * NB + b0 + row) * NH + ch * 8) = hv;
    }

    // ---- GEMM: A row = seq = col (validated), 60 MFMAs/wave ----
    const _Float16* hrow = &H[cur][col][q * 8];
    floatx4 cR0 = {0,0,0,0}, cZ0 = {0,0,0,0}, cN0 = {0,0,0,0}, cI0 = {0,0,0,0};
    floatx4 cR1 = {0,0,0,0}, cZ1 = {0,0,0,0}, cN1 = {0,0,0,0}, cI1 = {0,0,0,0};
#define KGRP(k) { \
    half8 a  = *(const half8*)(hrow + (k) * 32); \
    half8 n0 = *(const half8*)(wnW + (size_t)(k) * 512); \
    half8 n1 = *(const half8*)(wnW + (size_t)(8 + (k)) * 512); \
    cR0 = MFMA16(a, R0_##k, cR0); cR1 = MFMA16(a, R1_##k, cR1); \
    cZ0 = MFMA16(a, Z0_##k, cZ0); cZ1 = MFMA16(a, Z1_##k, cZ1); \
    cN0 = MFMA16(a, n0, cN0);     cN1 = MFMA16(a, n1, cN1); }
    KGRP(0) KGRP(1) KGRP(2) KGRP(3) KGRP(4)
    half8 ia0 = sI0[0], ib0 = sI1[0];      // frag kb=8 (used at k=8)
    KGRP(5)
    half8 ia1 = sI0[64], ib1 = sI1[64];    // frag kb=9 (used at k=9)
    KGRP(6) KGRP(7)
#undef KGRP
    { half8 a = *(const half8*)(hrow + 8 * 32);
      cR0 = MFMA16(a, R0_8, cR0); cR1 = MFMA16(a, R1_8, cR1);
      cZ0 = MFMA16(a, Z0_8, cZ0); cZ1 = MFMA16(a, Z1_8, cZ1);
      cI0 = MFMA16(a, ia0, cI0);  cI1 = MFMA16(a, ib0, cI1); }
    { half8 a = *(const half8*)(hrow + 9 * 32);
      cR0 = MFMA16(a, R0_9, cR0); cR1 = MFMA16(a, R1_9, cR1);
      cZ0 = MFMA16(a, Z0_9, cZ0); cZ1 = MFMA16(a, Z1_9, cZ1);
      cI0 = MFMA16(a, ia1, cI0);  cI1 = MFMA16(a, ib1, cI1); }

    // ---- in-register epilogue: lane owns (j0,j1) x (seqs q*4..q*4+3) ----
#define GATE(m, hvar, CR, CZ, CN, CI, BR_, BZ_, BI_, BH_, J) { \
    float rr = sigm(CR[m] + BR_); \
    float zz = sigm(CZ[m] + BZ_); \
    float nn = tanh_f(CI[m] + BI_ + rr * (CN[m] + BH_)); \
    hvar = (1.0f - zz) * nn + zz * hvar; \
    H[nxt][q * 4 + (m)][J] = (_Float16)hvar; }
    GATE(0, h00, cR0, cZ0, cN0, cI0, br0, bz0, bin0, bhn0, j0)
    GATE(1, h01, cR0, cZ0, cN0, cI0, br0, bz0, bin0, bhn0, j0)
    GATE(2, h02, cR0, cZ0, cN0, cI0, br0, bz0, bin0, bhn0, j0)
    GATE(3, h03, cR0, cZ0, cN0, cI0, br0, bz0, bin0, bhn0, j0)
    GATE(0, h10, cR1, cZ1, cN1, cI1, br1, bz1, bin1, bhn1, j1)
    GATE(1, h11, cR1, cZ1, cN1, cI1, br1, bz1, bin1, bhn1, j1)
    GATE(2, h12, cR1, cZ1, cN1, cI1, br1, bz1, bin1, bhn1, j1)
    GATE(3, h13, cR1, cZ1, cN1, cI1, br1, bz1, bin1, bhn1, j1)
#undef GATE
    if (t + 1 < NT) {
      H[nxt][w][256 + lane]     = (_Float16)xv0;
      H[nxt][w + 8][256 + lane] = (_Float16)xv1;
    }

    __syncthreads();   // the single per-step barrier
  }

  // ---- final dump: h_{NT-1} lives in H[0] (NT even) ----
  {
    int row = tid >> 5, ch = tid & 31;
    float4 hv = *(const float4*)&H[0][row][ch * 8];
    *(float4*)(HD + ((size_t)(NT - 1) * NB + b0 + row) * NH + ch * 8) = hv;
  }
}

// ---------------- epilogue: out[t][b] = HD[t][b][:] . w_out + b_out ----------------
__global__ __launch_bounds__(256) void gru_out_kernel(
    const _Float16* __restrict__ HD, const float* __restrict__ w_out,
    const float* __restrict__ b_out, float* __restrict__ out)
{
  __shared__ __align__(16) _Float16 WL[NH];
  int tid = threadIdx.x;
  WL[tid] = (_Float16)w_out[tid];
  __syncthreads();
  int gid = blockIdx.x * 256 + tid;          // gid = t*NB + b
  const float4* hp = (const float4*)(HD + (size_t)gid * NH);
  const float4* wp = (const float4*)WL;
  float acc = 0.0f;
  #pragma unroll
  for (int i = 0; i < NH / 8; ++i) {
    float4 hv = hp[i];
    float4 wv = wp[i];
    acc = FDOT(hv.x, wv.x, acc);
    acc = FDOT(hv.y, wv.y, acc);
    acc = FDOT(hv.z, wv.z, acc);
    acc = FDOT(hv.w, wv.w, acc);
  }
  out[gid] = acc + b_out[0];
}

extern "C" void kernel_launch(void* const* d_in, const int* in_sizes, int n_in,
                              void* d_out, int out_size, void* d_ws, size_t ws_size,
                              hipStream_t stream) {
  const float* x     = (const float*)d_in[0];
  const float* w_ih  = (const float*)d_in[1];
  const float* w_hh  = (const float*)d_in[2];
  const float* b_ih  = (const float*)d_in[3];
  const float* b_hh  = (const float*)d_in[4];
  const float* w_out = (const float*)d_in[5];
  const float* b_out = (const float*)d_in[6];
  float* out = (float*)d_out;

  _Float16* wb = (_Float16*)d_ws;            // 480 KB packed B fragments
  _Float16* HD = wb + WB_N;                  // 64 MB hidden-state dump (16B-aligned)

  gru_prep_kernel<<<(WB_N + 255) / 256, 256, 0, stream>>>(w_ih, w_hh, wb);
  gru_kernel<<<NBLK, THR, 0, stream>>>(x, b_ih, b_hh, wb, HD, out);
  gru_out_kernel<<<(NT * NB) / 256, 256, 0, stream>>>(HD, w_out, b_out, out);
}

// Round 8
// 1028.151 us; speedup vs baseline: 2.5279x; 1.2511x over previous
//
#include <hip/hip_runtime.h>

typedef _Float16 half8 __attribute__((ext_vector_type(8)));
typedef _Float16 f16x2 __attribute__((ext_vector_type(2)));
typedef float floatx4 __attribute__((ext_vector_type(4)));

#define NB 256    // batch
#define NT 512    // time
#define NI 64     // input
#define NH 256    // hidden
#define NSEQ 16   // sequences per block
#define NBLK (NB / NSEQ)   // 16 blocks
#define THR 512            // 8 waves, 2 waves/SIMD
#define HS 344             // H row stride in f16

// B-fragment pack (VALIDATED R9/R10): 480 frags x 64 lanes x 8 f16.
// Cols: [0,256)=r, [256,512)=z, [512,768)=h_n, [768,1024)=i_n. K: [0,256)=h, [256,320)=x.
// frag f: r: tt*10+kb; z: 160+tt*10+kb; h_n: 320+tt*8+kb (kb<8); i_n: 448+tt*2+(kb-8).
// wb[f*512 + lane*8 + i] = W[k = kb*32 + (lane>>4)*8 + i][n = tt*16 + (lane&15)]
#define WB_N (480 * 512)

__global__ __launch_bounds__(256) void gru_prep_kernel(
    const float* __restrict__ w_ih, const float* __restrict__ w_hh,
    _Float16* __restrict__ wb)
{
  int n = blockIdx.x * 256 + threadIdx.x;
  if (n >= WB_N) return;
  int i = n & 7, l = (n >> 3) & 63, f = n >> 9;
  int q = l >> 4, col = l & 15;
  int tt, kb, gate;
  if (f < 160)      { tt = f / 10;               kb = f % 10;        gate = 0; }
  else if (f < 320) { int f2 = f - 160; tt = f2 / 10; kb = f2 % 10;  gate = 1; }
  else if (f < 448) { int f3 = f - 320; tt = f3 / 8;  kb = f3 % 8;   gate = 2; }
  else              { int f4 = f - 448; tt = f4 / 2;  kb = 8 + (f4 & 1); gate = 3; }
  int j = (tt & 15) * 16 + col;
  int k = kb * 32 + q * 8 + i;
  float v;
  if (gate == 0)      v = (k < 256) ? w_hh[(0   + j) * 256 + k] : w_ih[(0   + j) * 64 + (k - 256)];
  else if (gate == 1) v = (k < 256) ? w_hh[(256 + j) * 256 + k] : w_ih[(256 + j) * 64 + (k - 256)];
  else if (gate == 2) v = w_hh[(512 + j) * 256 + k];
  else                v = w_ih[(512 + j) * 64 + (k - 256)];
  wb[n] = (_Float16)v;
}

__device__ __forceinline__ float sigm(float v) {
  return __builtin_amdgcn_rcpf(1.0f + __expf(-v));
}
__device__ __forceinline__ float tanh_f(float v) {
  return 1.0f - 2.0f * __builtin_amdgcn_rcpf(1.0f + __expf(2.0f * v));
}

#define MFMA16(a, b, c) __builtin_amdgcn_mfma_f32_16x16x32_f16(a, b, c, 0, 0, 0)
#define FDOT(W, X, A) __builtin_amdgcn_fdot2(__builtin_bit_cast(f16x2, W), \
                                             __builtin_bit_cast(f16x2, X), A, false)

// ---------------- batched MFMA recurrence: 1 block = 16 sequences ----------------
// R18 = R12 VERBATIM (the 1094-us best) with exactly ONE change: the occupancy
// attribute. Ledger: R12's "+v" pins spilled because the allocator budgeted 128
// regs (VGPR_Count=128); R13 proved the allocator WILL allocate 244 when the
// budget is truly raised; R17's waves_per_eu(2,2) was silently overridden by the
// coexisting __launch_bounds__ (which expands to its own amdgpu-waves-per-eu).
// Fix: NO __launch_bounds__; sole attributes amdgpu_flat_work_group_size(512,512)
// + amdgpu_waves_per_eu(2,2) -> budget 256/wave. Demand ~238 (128 pins + ~110
// live) <= 256. LDS 153KB already caps occupancy at 1 block/CU = 2 waves/SIMD,
// so max=2 costs nothing we had.
// At residency, per-step/CU: LDS ~3100-3400 cyc (A 80 + WN 128 b128 reads +
// gate/xv writes + HD + conflicts) = binding; VMEM only i_n (~500); MFMA
// 580/SIMD; epilogue VALU — overlapped. Predict ~700-820 us.
// Failure signature: VGPR_Count=128 & dur~1094 -> compiler residency path dead,
// pivot to 24-block hidden-split cooperative design.
__global__ __attribute__((amdgpu_flat_work_group_size(THR, THR),
                          amdgpu_waves_per_eu(2, 2)))
void gru_kernel(
    const float* __restrict__ x,      // [B, T, I]
    const float* __restrict__ b_ih,   // [768]
    const float* __restrict__ b_hh,   // [768]
    const _Float16* __restrict__ wb,  // packed B fragments
    _Float16* __restrict__ HD,        // [NT][NB][NH] f16 hidden-state dump
    float* __restrict__ out)          // unused here (kept for symmetry)
{
  __shared__ __align__(16) _Float16 H[2][NSEQ][HS];   // 22016 B, double-buffered
  __shared__ __align__(16) _Float16 WN[128 * 512];    // 131072 B: n-gate frags (16 tiles)

  const int tid  = threadIdx.x;
  const int lane = tid & 63;
  const int w    = tid >> 6;        // wave 0..7
  const int q    = lane >> 4;       // quad 0..3
  const int col  = lane & 15;
  const int b0   = blockIdx.x * NSEQ;
  const int j0   = (2 * w) * 16 + col;      // tile t0 = 2w
  const int j1   = j0 + 16;                 // tile t1 = 2w+1

  const _Float16* wbL = wb + (size_t)lane * 8;

  // ---- stage n-gate frags (wb frags [320,448)) to LDS: 128 KB coalesced ----
  {
    const float4* src = (const float4*)(wb + (size_t)320 * 512);
    float4* dst = (float4*)WN;
    #pragma unroll
    for (int it = 0; it < 16; ++it) dst[tid + it * THR] = src[tid + it * THR];
  }
  // wave's n frags: tile t0 -> frag 16w + k, tile t1 -> frag 16w+8+k
  const _Float16* wnW = WN + (size_t)(16 * w) * 512 + (size_t)lane * 8;

  // ---- persistent B fragments: r + z both tiles (32 x half8 = 128 VGPR) ----
#define LR(T, k) half8 R##T##_##k = *(const half8*)(wbL + (size_t)((2 * w + T) * 10 + (k)) * 512);
  LR(0,0) LR(0,1) LR(0,2) LR(0,3) LR(0,4) LR(0,5) LR(0,6) LR(0,7) LR(0,8) LR(0,9)
  LR(1,0) LR(1,1) LR(1,2) LR(1,3) LR(1,4) LR(1,5) LR(1,6) LR(1,7) LR(1,8) LR(1,9)
#undef LR
#define LZ(T, k) half8 Z##T##_##k = *(const half8*)(wbL + (size_t)(160 + (2 * w + T) * 10 + (k)) * 512);
  LZ(0,0) LZ(0,1) LZ(0,2) LZ(0,3) LZ(0,4) LZ(0,5) LZ(0,6) LZ(0,7) LZ(0,8) LZ(0,9)
  LZ(1,0) LZ(1,1) LZ(1,2) LZ(1,3) LZ(1,4) LZ(1,5) LZ(1,6) LZ(1,7) LZ(1,8) LZ(1,9)
#undef LZ
  // Pin them: asm identity is opaque -> not rematerializable -> must stay in regs.
  asm("" : "+v"(R0_0), "+v"(R0_1), "+v"(R0_2), "+v"(R0_3), "+v"(R0_4),
           "+v"(R0_5), "+v"(R0_6), "+v"(R0_7), "+v"(R0_8), "+v"(R0_9));
  asm("" : "+v"(R1_0), "+v"(R1_1), "+v"(R1_2), "+v"(R1_3), "+v"(R1_4),
           "+v"(R1_5), "+v"(R1_6), "+v"(R1_7), "+v"(R1_8), "+v"(R1_9));
  asm("" : "+v"(Z0_0), "+v"(Z0_1), "+v"(Z0_2), "+v"(Z0_3), "+v"(Z0_4),
           "+v"(Z0_5), "+v"(Z0_6), "+v"(Z0_7), "+v"(Z0_8), "+v"(Z0_9));
  asm("" : "+v"(Z1_0), "+v"(Z1_1), "+v"(Z1_2), "+v"(Z1_3), "+v"(Z1_4),
           "+v"(Z1_5), "+v"(Z1_6), "+v"(Z1_7), "+v"(Z1_8), "+v"(Z1_9));

  // ---- i_n stream pointers (2 frags/tile, re-read from L2 each step; loop-variant) ----
  uintptr_t pI0 = (uintptr_t)(wbL + (size_t)(448 + (2 * w) * 2) * 512);
  uintptr_t pI1 = (uintptr_t)(wbL + (size_t)(448 + (2 * w + 1) * 2) * 512);

  const float br0  = b_ih[j0] + b_hh[j0];
  const float bz0  = b_ih[256 + j0] + b_hh[256 + j0];
  const float bin0 = b_ih[512 + j0];
  const float bhn0 = b_hh[512 + j0];
  const float br1  = b_ih[j1] + b_hh[j1];
  const float bz1  = b_ih[256 + j1] + b_hh[256 + j1];
  const float bin1 = b_ih[512 + j1];
  const float bhn1 = b_hh[512 + j1];

  // ---- init: zero H (both buffers), then x(t=0) into H[0] ----
  {
    float4* hz = (float4*)H;
    #pragma unroll
    for (int it = 0; it < 3; ++it) {
      int idx = tid + it * THR;
      if (idx < (int)(sizeof(H) / 16)) hz[idx] = float4{0, 0, 0, 0};
    }
  }
  __syncthreads();
  H[0][w][256 + lane]     = (_Float16)x[(size_t)(b0 + w)     * (NT * NI) + lane];
  H[0][w + 8][256 + lane] = (_Float16)x[(size_t)(b0 + w + 8) * (NT * NI) + lane];
  float h00 = 0.0f, h01 = 0.0f, h02 = 0.0f, h03 = 0.0f;
  float h10 = 0.0f, h11 = 0.0f, h12 = 0.0f, h13 = 0.0f;
  const float* xp0 = x + (size_t)(b0 + w)     * (NT * NI) + 64 + lane;
  const float* xp1 = x + (size_t)(b0 + w + 8) * (NT * NI) + 64 + lane;
  __syncthreads();

  for (int t = 0; t < NT; ++t) {
    const int cur = t & 1, nxt = cur ^ 1;
    // keep i-stream loads loop-variant (no LICM hoist -> no extra persistent regs)
    asm("" : "+v"(pI0), "+v"(pI1));
    const half8* sI0 = (const half8*)pI0;
    const half8* sI1 = (const half8*)pI1;

    float xv0 = 0.0f, xv1 = 0.0f;
    if (t + 1 < NT) { xv0 = xp0[(size_t)t * 64]; xv1 = xp1[(size_t)t * 64]; }

    // ---- dump h_{t-1} (h-part of H[cur]) to HD[t-1]: all 512 threads ----
    if (t > 0) {
      int row = tid >> 5, ch = tid & 31;
      float4 hv = *(const float4*)&H[cur][row][ch * 8];
      *(float4*)(HD + ((size_t)(t - 1) * NB + b0 + row) * NH + ch * 8) = hv;
    }

    // ---- GEMM: A row = seq = col (validated), 60 MFMAs/wave ----
    const _Float16* hrow = &H[cur][col][q * 8];
    floatx4 cR0 = {0,0,0,0}, cZ0 = {0,0,0,0}, cN0 = {0,0,0,0}, cI0 = {0,0,0,0};
    floatx4 cR1 = {0,0,0,0}, cZ1 = {0,0,0,0}, cN1 = {0,0,0,0}, cI1 = {0,0,0,0};
#define KGRP(k) { \
    half8 a  = *(const half8*)(hrow + (k) * 32); \
    half8 n0 = *(const half8*)(wnW + (size_t)(k) * 512); \
    half8 n1 = *(const half8*)(wnW + (size_t)(8 + (k)) * 512); \
    cR0 = MFMA16(a, R0_##k, cR0); cR1 = MFMA16(a, R1_##k, cR1); \
    cZ0 = MFMA16(a, Z0_##k, cZ0); cZ1 = MFMA16(a, Z1_##k, cZ1); \
    cN0 = MFMA16(a, n0, cN0);     cN1 = MFMA16(a, n1, cN1); }
    KGRP(0) KGRP(1) KGRP(2) KGRP(3) KGRP(4)
    half8 ia0 = sI0[0], ib0 = sI1[0];      // frag kb=8 (used at k=8)
    KGRP(5)
    half8 ia1 = sI0[64], ib1 = sI1[64];    // frag kb=9 (used at k=9)
    KGRP(6) KGRP(7)
#undef KGRP
    { half8 a = *(const half8*)(hrow + 8 * 32);
      cR0 = MFMA16(a, R0_8, cR0); cR1 = MFMA16(a, R1_8, cR1);
      cZ0 = MFMA16(a, Z0_8, cZ0); cZ1 = MFMA16(a, Z1_8, cZ1);
      cI0 = MFMA16(a, ia0, cI0);  cI1 = MFMA16(a, ib0, cI1); }
    { half8 a = *(const half8*)(hrow + 9 * 32);
      cR0 = MFMA16(a, R0_9, cR0); cR1 = MFMA16(a, R1_9, cR1);
      cZ0 = MFMA16(a, Z0_9, cZ0); cZ1 = MFMA16(a, Z1_9, cZ1);
      cI0 = MFMA16(a, ia1, cI0);  cI1 = MFMA16(a, ib1, cI1); }

    // ---- in-register epilogue: lane owns (j0,j1) x (seqs q*4..q*4+3) ----
#define GATE(m, hvar, CR, CZ, CN, CI, BR_, BZ_, BI_, BH_, J) { \
    float rr = sigm(CR[m] + BR_); \
    float zz = sigm(CZ[m] + BZ_); \
    float nn = tanh_f(CI[m] + BI_ + rr * (CN[m] + BH_)); \
    hvar = (1.0f - zz) * nn + zz * hvar; \
    H[nxt][q * 4 + (m)][J] = (_Float16)hvar; }
    GATE(0, h00, cR0, cZ0, cN0, cI0, br0, bz0, bin0, bhn0, j0)
    GATE(1, h01, cR0, cZ0, cN0, cI0, br0, bz0, bin0, bhn0, j0)
    GATE(2, h02, cR0, cZ0, cN0, cI0, br0, bz0, bin0, bhn0, j0)
    GATE(3, h03, cR0, cZ0, cN0, cI0, br0, bz0, bin0, bhn0, j0)
    GATE(0, h10, cR1, cZ1, cN1, cI1, br1, bz1, bin1, bhn1, j1)
    GATE(1, h11, cR1, cZ1, cN1, cI1, br1, bz1, bin1, bhn1, j1)
    GATE(2, h12, cR1, cZ1, cN1, cI1, br1, bz1, bin1, bhn1, j1)
    GATE(3, h13, cR1, cZ1, cN1, cI1, br1, bz1, bin1, bhn1, j1)
#undef GATE
    if (t + 1 < NT) {
      H[nxt][w][256 + lane]     = (_Float16)xv0;
      H[nxt][w + 8][256 + lane] = (_Float16)xv1;
    }

    __syncthreads();   // the single per-step barrier
  }

  // ---- final dump: h_{NT-1} lives in H[0] (NT even) ----
  {
    int row = tid >> 5, ch = tid & 31;
    float4 hv = *(const float4*)&H[0][row][ch * 8];
    *(float4*)(HD + ((size_t)(NT - 1) * NB + b0 + row) * NH + ch * 8) = hv;
  }
}

// ---------------- epilogue: out[t][b] = HD[t][b][:] . w_out + b_out ----------------
__global__ __launch_bounds__(256) void gru_out_kernel(
    const _Float16* __restrict__ HD, const float* __restrict__ w_out,
    const float* __restrict__ b_out, float* __restrict__ out)
{
  __shared__ __align__(16) _Float16 WL[NH];
  int tid = threadIdx.x;
  WL[tid] = (_Float16)w_out[tid];
  __syncthreads();
  int gid = blockIdx.x * 256 + tid;          // gid = t*NB + b
  const float4* hp = (const float4*)(HD + (size_t)gid * NH);
  const float4* wp = (const float4*)WL;
  float acc = 0.0f;
  #pragma unroll
  for (int i = 0; i < NH / 8; ++i) {
    float4 hv = hp[i];
    float4 wv = wp[i];
    acc = FDOT(hv.x, wv.x, acc);
    acc = FDOT(hv.y, wv.y, acc);
    acc = FDOT(hv.z, wv.z, acc);
    acc = FDOT(hv.w, wv.w, acc);
  }
  out[gid] = acc + b_out[0];
}

extern "C" void kernel_launch(void* const* d_in, const int* in_sizes, int n_in,
                              void* d_out, int out_size, void* d_ws, size_t ws_size,
                              hipStream_t stream) {
  const float* x     = (const float*)d_in[0];
  const float* w_ih  = (const float*)d_in[1];
  const float* w_hh  = (const float*)d_in[2];
  const float* b_ih  = (const float*)d_in[3];
  const float* b_hh  = (const float*)d_in[4];
  const float* w_out = (const float*)d_in[5];
  const float* b_out = (const float*)d_in[6];
  float* out = (float*)d_out;

  _Float16* wb = (_Float16*)d_ws;            // 480 KB packed B fragments
  _Float16* HD = wb + WB_N;                  // 64 MB hidden-state dump (16B-aligned)

  gru_prep_kernel<<<(WB_N + 255) / 256, 256, 0, stream>>>(w_ih, w_hh, wb);
  gru_kernel<<<NBLK, THR, 0, stream>>>(x, b_ih, b_hh, wb, HD, out);
  gru_out_kernel<<<(NT * NB) / 256, 256, 0, stream>>>(HD, w_out, b_out, out);
}